// Round 12
// baseline (505.617 us; speedup 1.0000x reference)
//
#include <hip/hip_runtime.h>
#include <math.h>

// DynamicSparseAttention via MFMA flash (f16 operands, fp32 accum):
// out = (O5 + Z^4 O1) / (S5 + Z^4 S1), e = 2^(s*log2e - m'), Z = S1.
// R12: R9 (best, 86us) + ONE change: skip the e^5 path when the whole
//   128-k group has 2^(5(tm-mr)) < 2^-24 — cvt_pkrtz makes b5 exact +0
//   there, so skipping its MFMAs/sums is bitwise identical.

typedef _Float16 h8 __attribute__((ext_vector_type(8)));
typedef float f4 __attribute__((ext_vector_type(4)));
typedef float f16v __attribute__((ext_vector_type(16)));
typedef unsigned int u4v __attribute__((ext_vector_type(4)));

constexpr int Sc = 2048, Hc = 16;
constexpr int KB = 64, NT = Sc / KB;
constexpr float LOG2E = 1.4426950408889634f;

__device__ __forceinline__ f16v mm32(h8 a, h8 b, f16v c) {
  return __builtin_amdgcn_mfma_f32_32x32x16_f16(a, b, c, 0, 0, 0);
}
__device__ __forceinline__ unsigned pku(float a, float b) {
  return __builtin_bit_cast(unsigned, __builtin_amdgcn_cvt_pkrtz(a, b));
}

__global__ __launch_bounds__(256, 2) void dsa_mfma(
    const float* __restrict__ Q, const float* __restrict__ K,
    const float* __restrict__ V, float* __restrict__ O) {
  __shared__ __align__(16) _Float16 smem[4][2][64 * 64];  // [buf][K|V], 64 KB

  const int tid = threadIdx.x;
  const int w = tid >> 6, lane = tid & 63, lm = lane & 31, hi = lane >> 5;
  const int swz = (lm & 7) << 3;

  // XCD-bijective swizzle: 512 blocks = 8 XCD x 64; each XCD owns 4 heads.
  const int blk = blockIdx.x;
  const int ww = (blk & 7) * 64 + (blk >> 3);
  const int qtb = ww & 15, bh = ww >> 4;
  const int b = bh >> 4, h = bh & 15;

  const size_t base = ((size_t)b * Sc * Hc + h) * 64;  // row stride = 1024 floats
  const float* Qb = Q + base;
  const float* Kb = K + base;
  const float* Vb = V + base;
  const int q0 = qtb * 128 + w * 32;

  // ---- Q fragments (B-operand): lane holds Q[q0+lm][s*16 + hi*8 + j]*log2e ----
  h8 qf[4];
#pragma unroll
  for (int s = 0; s < 4; ++s) {
    const float* p = Qb + (size_t)(q0 + lm) * 1024 + s * 16 + hi * 8;
    f4 a = *(const f4*)p, c = *(const f4*)(p + 4);
#pragma unroll
    for (int i = 0; i < 4; ++i) {
      qf[s][i] = (_Float16)(a[i] * LOG2E);
      qf[s][4 + i] = (_Float16)(c[i] * LOG2E);
    }
  }
  h8 ones;
#pragma unroll
  for (int i = 0; i < 8; ++i) ones[i] = (_Float16)1.0f;

  f16v O1[2] = {}, O5[2] = {};  // O^T[d][q], dtile 0/1
  f16v S1a = {}, S5a = {};      // ones-MFMA sum accumulators (all rows equal)
  float mr = -INFINITY;

  // ---- staging: K row-owner (krow=tid&63, 16 floats), V column-gather ----
  f4 kf[4];
  float vreg[2][8];
  const int krow = tid & 63, kq = tid >> 6;       // K: row krow, float cols kq*16..+16
  const int vd = tid & 63, vo0 = (tid >> 6) * 2;  // V: d-col vd, k-octets vo0, vo0+1

  auto LOADK = [&](int k0) {
#pragma unroll
    for (int j = 0; j < 4; ++j)
      kf[j] = *(const f4*)(Kb + (size_t)(k0 + krow) * 1024 + kq * 16 + 4 * j);
  };
  auto LOADV = [&](int k0) {  // coalesced: 64 lanes read consecutive d
#pragma unroll
    for (int i = 0; i < 2; ++i) {
      const float* p = Vb + (size_t)(k0 + (vo0 + i) * 8) * 1024 + vd;
#pragma unroll
      for (int j = 0; j < 8; ++j) vreg[i][j] = p[(size_t)j * 1024];
    }
  };
  auto STORE = [&](int buf) {
    _Float16* Ks = &smem[buf][0][0];
    _Float16* Vts = &smem[buf][1][0];
#pragma unroll
    for (int i = 0; i < 2; ++i) {  // K: two b128 stores
      u4v wv = {pku(kf[2 * i][0], kf[2 * i][1]), pku(kf[2 * i][2], kf[2 * i][3]),
                pku(kf[2 * i + 1][0], kf[2 * i + 1][1]), pku(kf[2 * i + 1][2], kf[2 * i + 1][3])};
      int col = (kq * 16 + 8 * i) ^ ((krow & 7) << 3);
      *(h8*)&Ks[krow * 64 + col] = __builtin_bit_cast(h8, wv);
    }
#pragma unroll
    for (int i = 0; i < 2; ++i) {  // V^T: b128 stores
      u4v wv = {pku(vreg[i][0], vreg[i][1]), pku(vreg[i][2], vreg[i][3]),
                pku(vreg[i][4], vreg[i][5]), pku(vreg[i][6], vreg[i][7])};
      int col = ((vo0 + i) * 8) ^ ((vd & 7) << 3);
      *(h8*)&Vts[vd * 64 + col] = __builtin_bit_cast(h8, wv);
    }
  };

  auto QK = [&](int cur, f16v sc[2]) {
    const _Float16* Ks = &smem[cur][0][0];
    sc[0] = f16v{};
    sc[1] = f16v{};
    __builtin_amdgcn_s_setprio(1);
#pragma unroll
    for (int s = 0; s < 4; ++s) {
      h8 a0 = *(const h8*)&Ks[lm * 64 + ((s * 16 + hi * 8) ^ swz)];
      h8 a1 = *(const h8*)&Ks[(32 + lm) * 64 + ((s * 16 + hi * 8) ^ swz)];
      sc[0] = mm32(a0, qf[s], sc[0]);
      sc[1] = mm32(a1, qf[s], sc[1]);
    }
    __builtin_amdgcn_s_setprio(0);
  };

  auto PVX = [&](int cur, f16v sc[2], bool do5) {  // exp, in-reg P frags, PV + sums
    const _Float16* Vts = &smem[cur][1][0];
#pragma unroll
    for (int s = 0; s < 4; ++s) {
      const int kh = s >> 1, s8 = (s & 1) * 8;
      float e[8];
#pragma unroll
      for (int j = 0; j < 8; ++j) e[j] = __builtin_amdgcn_exp2f(sc[kh][s8 + j] - mr);
      auto rA = __builtin_amdgcn_permlane32_swap(pku(e[0], e[1]), pku(e[4], e[5]), false, false);
      auto rB = __builtin_amdgcn_permlane32_swap(pku(e[2], e[3]), pku(e[6], e[7]), false, false);
      u4v bwE = {(unsigned)rA[0], (unsigned)rB[0], (unsigned)rA[1], (unsigned)rB[1]};
      h8 bE = __builtin_bit_cast(h8, bwE);

      h8 v0 = *(const h8*)&Vts[lm * 64 + ((s * 16 + hi * 8) ^ swz)];
      h8 v1 = *(const h8*)&Vts[(32 + lm) * 64 + ((s * 16 + hi * 8) ^ swz)];

      if (do5) {
        h8 b2 = bE * bE, b4 = b2 * b2, b5 = b4 * bE;  // v_pk_mul_f16
        __builtin_amdgcn_s_setprio(1);
        O1[0] = mm32(v0, bE, O1[0]);
        O1[1] = mm32(v1, bE, O1[1]);
        S1a = mm32(ones, bE, S1a);
        O5[0] = mm32(v0, b5, O5[0]);
        O5[1] = mm32(v1, b5, O5[1]);
        S5a = mm32(ones, b5, S5a);
        __builtin_amdgcn_s_setprio(0);
      } else {
        __builtin_amdgcn_s_setprio(1);
        O1[0] = mm32(v0, bE, O1[0]);
        O1[1] = mm32(v1, bE, O1[1]);
        S1a = mm32(ones, bE, S1a);
        __builtin_amdgcn_s_setprio(0);
      }
    }
  };

  // ---- prologue: fill buffers 0,1; tile 2 in regs ----
  LOADK(0);
  LOADV(0);
  STORE(0);
  LOADK(KB);
  LOADV(KB);
  STORE(1);
  LOADK(2 * KB);
  LOADV(2 * KB);
  __syncthreads();

  // ---- main loop: 2 tiles per barrier; reads {t,t+1}&3, stores {t+2,t+3}&3 ----
#pragma unroll 1
  for (int t = 0; t < NT; t += 2) {
    if (t + 2 < NT) STORE((t + 2) & 3);
    if (t + 3 < NT) {
      LOADK((t + 3) * KB);
      LOADV((t + 3) * KB);
    }

    f16v s0[2], s1[2];
    QK(t & 3, s0);
    QK((t + 1) & 3, s1);

    // combined max over both tiles (128 k), single rescale check
    float m16[16];
#pragma unroll
    for (int r = 0; r < 16; ++r)
      m16[r] = fmaxf(fmaxf(s0[0][r], s0[1][r]), fmaxf(s1[0][r], s1[1][r]));
#pragma unroll
    for (int d = 8; d >= 1; d >>= 1)
#pragma unroll
      for (int r = 0; r < d; ++r) m16[r] = fmaxf(m16[r], m16[r + d]);
    float tm = fmaxf(m16[0], __shfl_xor(m16[0], 32));
    if (__any(tm > mr)) {
      float nm = fmaxf(mr, tm);
      float f = __builtin_amdgcn_exp2f(mr - nm);
      float f2 = f * f, f5 = f2 * f2 * f;
      mr = nm;
      S1a *= f;
      S5a *= f5;
#pragma unroll
      for (int dt = 0; dt < 2; ++dt) {
        O1[dt] *= f;
        O5[dt] *= f5;
      }
    }
    // e5 path: 2^(5(tm-mr)) < 2^-24 -> cvt_pkrtz truncates ALL b5 to exact +0,
    // so skipping the O5/S5a MFMAs is bitwise identical.
    const bool do5 = __any(tm > mr - 4.8f);

    PVX(t & 3, s0, do5);

    if (t + 3 < NT) STORE((t + 3) & 3);
    if (t + 4 < NT) {
      LOADK((t + 4) * KB);
      LOADV((t + 4) * KB);
    }

    PVX((t + 1) & 3, s1, do5);

    __syncthreads();
  }

  // ---- epilogue: out = (O5 + Z^4 O1) / (S5 + Z^4 S1), Z = S1 ----
  const float z = S1a[0], z2 = z * z, z4 = z2 * z2;
  const float inv = 1.0f / (S5a[0] + z4 * S1a[0]);
#pragma unroll
  for (int dt = 0; dt < 2; ++dt)
#pragma unroll
    for (int i = 0; i < 4; ++i) {
      f4 o;
#pragma unroll
      for (int j = 0; j < 4; ++j)
        o[j] = (O5[dt][4 * i + j] + z4 * O1[dt][4 * i + j]) * inv;
      *(f4*)(O + base + (size_t)(q0 + lm) * 1024 + dt * 32 + 8 * i + 4 * hi) = o;
    }
}

extern "C" void kernel_launch(void* const* d_in, const int* in_sizes, int n_in,
                              void* d_out, int out_size, void* d_ws, size_t ws_size,
                              hipStream_t stream) {
  const float* q = (const float*)d_in[0];
  const float* k = (const float*)d_in[1];
  const float* v = (const float*)d_in[2];
  float* o = (float*)d_out;
  dsa_mfma<<<dim3(512), dim3(256), 0, stream>>>(q, k, v, o);
}

// Round 13
// 85.039 us; speedup vs baseline: 5.9457x; 5.9457x over previous
//
#include <hip/hip_runtime.h>
#include <math.h>

// DynamicSparseAttention via MFMA flash (f16 operands, fp32 accum):
// out = (O5 + Z^4 O1) / (S5 + Z^4 S1), e = 2^(s*log2e - m'), Z = S1.
// R13: R9 (best, 86us) + minimal e5-skip: b5 ALWAYS computed (identical
//   liveness to R9); only the O5/S5a accumulator MFMAs sit behind a
//   wave-uniform branch. Skip iff 5*(tm-mr) <= -24.5: then every pkrtz'd
//   e^5 is < 2^-24 -> exact f16 +0 -> skipped MFMAs add exact zero.

typedef _Float16 h8 __attribute__((ext_vector_type(8)));
typedef float f4 __attribute__((ext_vector_type(4)));
typedef float f16v __attribute__((ext_vector_type(16)));
typedef unsigned int u4v __attribute__((ext_vector_type(4)));

constexpr int Sc = 2048, Hc = 16;
constexpr int KB = 64, NT = Sc / KB;
constexpr float LOG2E = 1.4426950408889634f;

__device__ __forceinline__ f16v mm32(h8 a, h8 b, f16v c) {
  return __builtin_amdgcn_mfma_f32_32x32x16_f16(a, b, c, 0, 0, 0);
}
__device__ __forceinline__ unsigned pku(float a, float b) {
  return __builtin_bit_cast(unsigned, __builtin_amdgcn_cvt_pkrtz(a, b));
}

__global__ __launch_bounds__(256, 2) void dsa_mfma(
    const float* __restrict__ Q, const float* __restrict__ K,
    const float* __restrict__ V, float* __restrict__ O) {
  __shared__ __align__(16) _Float16 smem[4][2][64 * 64];  // [buf][K|V], 64 KB

  const int tid = threadIdx.x;
  const int w = tid >> 6, lane = tid & 63, lm = lane & 31, hi = lane >> 5;
  const int swz = (lm & 7) << 3;

  // XCD-bijective swizzle: 512 blocks = 8 XCD x 64; each XCD owns 4 heads.
  const int blk = blockIdx.x;
  const int ww = (blk & 7) * 64 + (blk >> 3);
  const int qtb = ww & 15, bh = ww >> 4;
  const int b = bh >> 4, h = bh & 15;

  const size_t base = ((size_t)b * Sc * Hc + h) * 64;  // row stride = 1024 floats
  const float* Qb = Q + base;
  const float* Kb = K + base;
  const float* Vb = V + base;
  const int q0 = qtb * 128 + w * 32;

  // ---- Q fragments (B-operand): lane holds Q[q0+lm][s*16 + hi*8 + j]*log2e ----
  h8 qf[4];
#pragma unroll
  for (int s = 0; s < 4; ++s) {
    const float* p = Qb + (size_t)(q0 + lm) * 1024 + s * 16 + hi * 8;
    f4 a = *(const f4*)p, c = *(const f4*)(p + 4);
#pragma unroll
    for (int i = 0; i < 4; ++i) {
      qf[s][i] = (_Float16)(a[i] * LOG2E);
      qf[s][4 + i] = (_Float16)(c[i] * LOG2E);
    }
  }
  h8 ones;
#pragma unroll
  for (int i = 0; i < 8; ++i) ones[i] = (_Float16)1.0f;

  f16v O1[2] = {}, O5[2] = {};  // O^T[d][q], dtile 0/1
  f16v S1a = {}, S5a = {};      // ones-MFMA sum accumulators (all rows equal)
  float mr = -INFINITY;

  // ---- staging: K row-owner (krow=tid&63, 16 floats), V column-gather ----
  f4 kf[4];
  float vreg[2][8];
  const int krow = tid & 63, kq = tid >> 6;       // K: row krow, float cols kq*16..+16
  const int vd = tid & 63, vo0 = (tid >> 6) * 2;  // V: d-col vd, k-octets vo0, vo0+1

  auto LOADK = [&](int k0) {
#pragma unroll
    for (int j = 0; j < 4; ++j)
      kf[j] = *(const f4*)(Kb + (size_t)(k0 + krow) * 1024 + kq * 16 + 4 * j);
  };
  auto LOADV = [&](int k0) {  // coalesced: 64 lanes read consecutive d
#pragma unroll
    for (int i = 0; i < 2; ++i) {
      const float* p = Vb + (size_t)(k0 + (vo0 + i) * 8) * 1024 + vd;
#pragma unroll
      for (int j = 0; j < 8; ++j) vreg[i][j] = p[(size_t)j * 1024];
    }
  };
  auto STORE = [&](int buf) {
    _Float16* Ks = &smem[buf][0][0];
    _Float16* Vts = &smem[buf][1][0];
#pragma unroll
    for (int i = 0; i < 2; ++i) {  // K: two b128 stores
      u4v wv = {pku(kf[2 * i][0], kf[2 * i][1]), pku(kf[2 * i][2], kf[2 * i][3]),
                pku(kf[2 * i + 1][0], kf[2 * i + 1][1]), pku(kf[2 * i + 1][2], kf[2 * i + 1][3])};
      int col = (kq * 16 + 8 * i) ^ ((krow & 7) << 3);
      *(h8*)&Ks[krow * 64 + col] = __builtin_bit_cast(h8, wv);
    }
#pragma unroll
    for (int i = 0; i < 2; ++i) {  // V^T: b128 stores
      u4v wv = {pku(vreg[i][0], vreg[i][1]), pku(vreg[i][2], vreg[i][3]),
                pku(vreg[i][4], vreg[i][5]), pku(vreg[i][6], vreg[i][7])};
      int col = ((vo0 + i) * 8) ^ ((vd & 7) << 3);
      *(h8*)&Vts[vd * 64 + col] = __builtin_bit_cast(h8, wv);
    }
  };

  auto QK = [&](int cur, f16v sc[2]) {
    const _Float16* Ks = &smem[cur][0][0];
    sc[0] = f16v{};
    sc[1] = f16v{};
    __builtin_amdgcn_s_setprio(1);
#pragma unroll
    for (int s = 0; s < 4; ++s) {
      h8 a0 = *(const h8*)&Ks[lm * 64 + ((s * 16 + hi * 8) ^ swz)];
      h8 a1 = *(const h8*)&Ks[(32 + lm) * 64 + ((s * 16 + hi * 8) ^ swz)];
      sc[0] = mm32(a0, qf[s], sc[0]);
      sc[1] = mm32(a1, qf[s], sc[1]);
    }
    __builtin_amdgcn_s_setprio(0);
  };

  auto PVX = [&](int cur, f16v sc[2], bool do5) {  // exp, in-reg P frags, PV + sums
    const _Float16* Vts = &smem[cur][1][0];
#pragma unroll
    for (int s = 0; s < 4; ++s) {
      const int kh = s >> 1, s8 = (s & 1) * 8;
      float e[8];
#pragma unroll
      for (int j = 0; j < 8; ++j) e[j] = __builtin_amdgcn_exp2f(sc[kh][s8 + j] - mr);
      auto rA = __builtin_amdgcn_permlane32_swap(pku(e[0], e[1]), pku(e[4], e[5]), false, false);
      auto rB = __builtin_amdgcn_permlane32_swap(pku(e[2], e[3]), pku(e[6], e[7]), false, false);
      u4v bwE = {(unsigned)rA[0], (unsigned)rB[0], (unsigned)rA[1], (unsigned)rB[1]};
      h8 bE = __builtin_bit_cast(h8, bwE);
      h8 b2 = bE * bE, b4 = b2 * b2, b5 = b4 * bE;  // always computed (same liveness as R9)

      h8 v0 = *(const h8*)&Vts[lm * 64 + ((s * 16 + hi * 8) ^ swz)];
      h8 v1 = *(const h8*)&Vts[(32 + lm) * 64 + ((s * 16 + hi * 8) ^ swz)];
      __builtin_amdgcn_s_setprio(1);
      O1[0] = mm32(v0, bE, O1[0]);
      O1[1] = mm32(v1, bE, O1[1]);
      S1a = mm32(ones, bE, S1a);
      if (do5) {  // wave-uniform; skipped MFMAs would add exact +0
        O5[0] = mm32(v0, b5, O5[0]);
        O5[1] = mm32(v1, b5, O5[1]);
        S5a = mm32(ones, b5, S5a);
      }
      __builtin_amdgcn_s_setprio(0);
    }
  };

  // ---- prologue: fill buffers 0,1; tile 2 in regs ----
  LOADK(0);
  LOADV(0);
  STORE(0);
  LOADK(KB);
  LOADV(KB);
  STORE(1);
  LOADK(2 * KB);
  LOADV(2 * KB);
  __syncthreads();

  // ---- main loop: 2 tiles per barrier; reads {t,t+1}&3, stores {t+2,t+3}&3 ----
#pragma unroll 1
  for (int t = 0; t < NT; t += 2) {
    if (t + 2 < NT) STORE((t + 2) & 3);
    if (t + 3 < NT) {
      LOADK((t + 3) * KB);
      LOADV((t + 3) * KB);
    }

    f16v s0[2], s1[2];
    QK(t & 3, s0);
    QK((t + 1) & 3, s1);

    // combined max over both tiles (128 k), single rescale check
    float m16[16];
#pragma unroll
    for (int r = 0; r < 16; ++r)
      m16[r] = fmaxf(fmaxf(s0[0][r], s0[1][r]), fmaxf(s1[0][r], s1[1][r]));
#pragma unroll
    for (int d = 8; d >= 1; d >>= 1)
#pragma unroll
      for (int r = 0; r < d; ++r) m16[r] = fmaxf(m16[r], m16[r + d]);
    float tm = fmaxf(m16[0], __shfl_xor(m16[0], 32));
    if (__any(tm > mr)) {
      float nm = fmaxf(mr, tm);
      float f = __builtin_amdgcn_exp2f(mr - nm);
      float f2 = f * f, f5 = f2 * f2 * f;
      mr = nm;
      S1a *= f;
      S5a *= f5;
#pragma unroll
      for (int dt = 0; dt < 2; ++dt) {
        O1[dt] *= f;
        O5[dt] *= f5;
      }
    }
    // skip e5 accumulation iff 5*(tm-mr) <= -24.5: all f16 e^5 are exact +0
    const bool do5 = __any(tm > mr - 4.9f);

    PVX(t & 3, s0, do5);

    if (t + 3 < NT) STORE((t + 3) & 3);
    if (t + 4 < NT) {
      LOADK((t + 4) * KB);
      LOADV((t + 4) * KB);
    }

    PVX((t + 1) & 3, s1, do5);

    __syncthreads();
  }

  // ---- epilogue: out = (O5 + Z^4 O1) / (S5 + Z^4 S1), Z = S1 ----
  const float z = S1a[0], z2 = z * z, z4 = z2 * z2;
  const float inv = 1.0f / (S5a[0] + z4 * S1a[0]);
#pragma unroll
  for (int dt = 0; dt < 2; ++dt)
#pragma unroll
    for (int i = 0; i < 4; ++i) {
      f4 o;
#pragma unroll
      for (int j = 0; j < 4; ++j)
        o[j] = (O5[dt][4 * i + j] + z4 * O1[dt][4 * i + j]) * inv;
      *(f4*)(O + base + (size_t)(q0 + lm) * 1024 + dt * 32 + 8 * i + 4 * hi) = o;
    }
}

extern "C" void kernel_launch(void* const* d_in, const int* in_sizes, int n_in,
                              void* d_out, int out_size, void* d_ws, size_t ws_size,
                              hipStream_t stream) {
  const float* q = (const float*)d_in[0];
  const float* k = (const float*)d_in[1];
  const float* v = (const float*)d_in[2];
  float* o = (float*)d_out;
  dsa_mfma<<<dim3(512), dim3(256), 0, stream>>>(q, k, v, o);
}

// Round 14
// 80.465 us; speedup vs baseline: 6.2837x; 1.0569x over previous
//
#include <hip/hip_runtime.h>
#include <math.h>

// DynamicSparseAttention via MFMA flash (f16 operands, fp32 accum):
// out = (O5 + Z^4 O1) / (S5 + Z^4 S1), e = 2^(s*log2e - m'), Z = S1.
// R14: R13 + ONE change: S1/S5 sums via v_dot2_f32_f16 partials instead of
//   ones-MFMA. Frees ~36 VGPR (R13 was pinned at the 128 cap), removes 1/3
//   of MFMA issue and two 8-deep MFMA self-chains.

typedef _Float16 h8 __attribute__((ext_vector_type(8)));
typedef _Float16 h2 __attribute__((ext_vector_type(2)));
typedef __fp16 g2 __attribute__((ext_vector_type(2)));
typedef float f4 __attribute__((ext_vector_type(4)));
typedef float f16v __attribute__((ext_vector_type(16)));
typedef unsigned int u4v __attribute__((ext_vector_type(4)));

constexpr int Sc = 2048, Hc = 16;
constexpr int KB = 64, NT = Sc / KB;
constexpr float LOG2E = 1.4426950408889634f;

__device__ __forceinline__ f16v mm32(h8 a, h8 b, f16v c) {
  return __builtin_amdgcn_mfma_f32_32x32x16_f16(a, b, c, 0, 0, 0);
}
__device__ __forceinline__ unsigned pku(float a, float b) {
  return __builtin_bit_cast(unsigned, __builtin_amdgcn_cvt_pkrtz(a, b));
}
__device__ __forceinline__ float fdot2(h2 a, float c) {  // a.x + a.y + c
  const g2 one2 = {(__fp16)1.0f, (__fp16)1.0f};
  return __builtin_amdgcn_fdot2(__builtin_bit_cast(g2, a), one2, c, false);
}

__global__ __launch_bounds__(256, 2) void dsa_mfma(
    const float* __restrict__ Q, const float* __restrict__ K,
    const float* __restrict__ V, float* __restrict__ O) {
  __shared__ __align__(16) _Float16 smem[4][2][64 * 64];  // [buf][K|V], 64 KB

  const int tid = threadIdx.x;
  const int w = tid >> 6, lane = tid & 63, lm = lane & 31, hi = lane >> 5;
  const int swz = (lm & 7) << 3;

  // XCD-bijective swizzle: 512 blocks = 8 XCD x 64; each XCD owns 4 heads.
  const int blk = blockIdx.x;
  const int ww = (blk & 7) * 64 + (blk >> 3);
  const int qtb = ww & 15, bh = ww >> 4;
  const int b = bh >> 4, h = bh & 15;

  const size_t base = ((size_t)b * Sc * Hc + h) * 64;  // row stride = 1024 floats
  const float* Qb = Q + base;
  const float* Kb = K + base;
  const float* Vb = V + base;
  const int q0 = qtb * 128 + w * 32;

  // ---- Q fragments (B-operand): lane holds Q[q0+lm][s*16 + hi*8 + j]*log2e ----
  h8 qf[4];
#pragma unroll
  for (int s = 0; s < 4; ++s) {
    const float* p = Qb + (size_t)(q0 + lm) * 1024 + s * 16 + hi * 8;
    f4 a = *(const f4*)p, c = *(const f4*)(p + 4);
#pragma unroll
    for (int i = 0; i < 4; ++i) {
      qf[s][i] = (_Float16)(a[i] * LOG2E);
      qf[s][4 + i] = (_Float16)(c[i] * LOG2E);
    }
  }

  f16v O1[2] = {}, O5[2] = {};                     // O^T[d][q], dtile 0/1
  float S1p[2] = {0.f, 0.f}, S5p[2] = {0.f, 0.f};  // fdot2 sum partials
  float mr = -INFINITY;

  // ---- staging: K row-owner (krow=tid&63, 16 floats), V column-gather ----
  f4 kf[4];
  float vreg[2][8];
  const int krow = tid & 63, kq = tid >> 6;       // K: row krow, float cols kq*16..+16
  const int vd = tid & 63, vo0 = (tid >> 6) * 2;  // V: d-col vd, k-octets vo0, vo0+1

  auto LOADK = [&](int k0) {
#pragma unroll
    for (int j = 0; j < 4; ++j)
      kf[j] = *(const f4*)(Kb + (size_t)(k0 + krow) * 1024 + kq * 16 + 4 * j);
  };
  auto LOADV = [&](int k0) {  // coalesced: 64 lanes read consecutive d
#pragma unroll
    for (int i = 0; i < 2; ++i) {
      const float* p = Vb + (size_t)(k0 + (vo0 + i) * 8) * 1024 + vd;
#pragma unroll
      for (int j = 0; j < 8; ++j) vreg[i][j] = p[(size_t)j * 1024];
    }
  };
  auto STORE = [&](int buf) {
    _Float16* Ks = &smem[buf][0][0];
    _Float16* Vts = &smem[buf][1][0];
#pragma unroll
    for (int i = 0; i < 2; ++i) {  // K: two b128 stores
      u4v wv = {pku(kf[2 * i][0], kf[2 * i][1]), pku(kf[2 * i][2], kf[2 * i][3]),
                pku(kf[2 * i + 1][0], kf[2 * i + 1][1]), pku(kf[2 * i + 1][2], kf[2 * i + 1][3])};
      int col = (kq * 16 + 8 * i) ^ ((krow & 7) << 3);
      *(h8*)&Ks[krow * 64 + col] = __builtin_bit_cast(h8, wv);
    }
#pragma unroll
    for (int i = 0; i < 2; ++i) {  // V^T: b128 stores
      u4v wv = {pku(vreg[i][0], vreg[i][1]), pku(vreg[i][2], vreg[i][3]),
                pku(vreg[i][4], vreg[i][5]), pku(vreg[i][6], vreg[i][7])};
      int col = ((vo0 + i) * 8) ^ ((vd & 7) << 3);
      *(h8*)&Vts[vd * 64 + col] = __builtin_bit_cast(h8, wv);
    }
  };

  auto QK = [&](int cur, f16v sc[2]) {
    const _Float16* Ks = &smem[cur][0][0];
    sc[0] = f16v{};
    sc[1] = f16v{};
    __builtin_amdgcn_s_setprio(1);
#pragma unroll
    for (int s = 0; s < 4; ++s) {
      h8 a0 = *(const h8*)&Ks[lm * 64 + ((s * 16 + hi * 8) ^ swz)];
      h8 a1 = *(const h8*)&Ks[(32 + lm) * 64 + ((s * 16 + hi * 8) ^ swz)];
      sc[0] = mm32(a0, qf[s], sc[0]);
      sc[1] = mm32(a1, qf[s], sc[1]);
    }
    __builtin_amdgcn_s_setprio(0);
  };

  auto PVX = [&](int cur, f16v sc[2], bool do5) {  // exp, in-reg P frags, PV + sums
    const _Float16* Vts = &smem[cur][1][0];
#pragma unroll
    for (int s = 0; s < 4; ++s) {
      const int kh = s >> 1, s8 = (s & 1) * 8, par = s & 1;
      float e[8];
#pragma unroll
      for (int j = 0; j < 8; ++j) e[j] = __builtin_amdgcn_exp2f(sc[kh][s8 + j] - mr);
      auto rA = __builtin_amdgcn_permlane32_swap(pku(e[0], e[1]), pku(e[4], e[5]), false, false);
      auto rB = __builtin_amdgcn_permlane32_swap(pku(e[2], e[3]), pku(e[6], e[7]), false, false);
      u4v bwE = {(unsigned)rA[0], (unsigned)rB[0], (unsigned)rA[1], (unsigned)rB[1]};
      h8 bE = __builtin_bit_cast(h8, bwE);
      h8 b2 = bE * bE, b4 = b2 * b2, b5 = b4 * bE;  // v_pk_mul_f16

      // S1 partial: every f16 in bE belongs to this lane's query (col = lm)
      float sp = fdot2(h2{bE[0], bE[1]}, 0.f);
      sp = fdot2(h2{bE[2], bE[3]}, sp);
      sp = fdot2(h2{bE[4], bE[5]}, sp);
      sp = fdot2(h2{bE[6], bE[7]}, sp);
      S1p[par] += sp;

      h8 v0 = *(const h8*)&Vts[lm * 64 + ((s * 16 + hi * 8) ^ swz)];
      h8 v1 = *(const h8*)&Vts[(32 + lm) * 64 + ((s * 16 + hi * 8) ^ swz)];
      __builtin_amdgcn_s_setprio(1);
      O1[0] = mm32(v0, bE, O1[0]);
      O1[1] = mm32(v1, bE, O1[1]);
      if (do5) {  // wave-uniform; skipped terms are exact +0
        float s5 = fdot2(h2{b5[0], b5[1]}, 0.f);
        s5 = fdot2(h2{b5[2], b5[3]}, s5);
        s5 = fdot2(h2{b5[4], b5[5]}, s5);
        s5 = fdot2(h2{b5[6], b5[7]}, s5);
        S5p[par] += s5;
        O5[0] = mm32(v0, b5, O5[0]);
        O5[1] = mm32(v1, b5, O5[1]);
      }
      __builtin_amdgcn_s_setprio(0);
    }
  };

  // ---- prologue: fill buffers 0,1; tile 2 in regs ----
  LOADK(0);
  LOADV(0);
  STORE(0);
  LOADK(KB);
  LOADV(KB);
  STORE(1);
  LOADK(2 * KB);
  LOADV(2 * KB);
  __syncthreads();

  // ---- main loop: 2 tiles per barrier; reads {t,t+1}&3, stores {t+2,t+3}&3 ----
#pragma unroll 1
  for (int t = 0; t < NT; t += 2) {
    if (t + 2 < NT) STORE((t + 2) & 3);
    if (t + 3 < NT) {
      LOADK((t + 3) * KB);
      LOADV((t + 3) * KB);
    }

    f16v s0[2], s1[2];
    QK(t & 3, s0);
    QK((t + 1) & 3, s1);

    // combined max over both tiles (128 k), single rescale check
    float m16[16];
#pragma unroll
    for (int r = 0; r < 16; ++r)
      m16[r] = fmaxf(fmaxf(s0[0][r], s0[1][r]), fmaxf(s1[0][r], s1[1][r]));
#pragma unroll
    for (int d = 8; d >= 1; d >>= 1)
#pragma unroll
      for (int r = 0; r < d; ++r) m16[r] = fmaxf(m16[r], m16[r + d]);
    float tm = fmaxf(m16[0], __shfl_xor(m16[0], 32));
    if (__any(tm > mr)) {
      float nm = fmaxf(mr, tm);
      float f = __builtin_amdgcn_exp2f(mr - nm);
      float f2 = f * f, f5 = f2 * f2 * f;
      mr = nm;
      S1p[0] *= f;
      S1p[1] *= f;
      S5p[0] *= f5;
      S5p[1] *= f5;
#pragma unroll
      for (int dt = 0; dt < 2; ++dt) {
        O1[dt] *= f;
        O5[dt] *= f5;
      }
    }
    // skip e5 accumulation iff 5*(tm-mr) <= -24.5: all f16 e^5 are exact +0
    const bool do5 = __any(tm > mr - 4.9f);

    PVX(t & 3, s0, do5);

    if (t + 3 < NT) STORE((t + 3) & 3);
    if (t + 4 < NT) {
      LOADK((t + 4) * KB);
      LOADV((t + 4) * KB);
    }

    PVX((t + 1) & 3, s1, do5);

    __syncthreads();
  }

  // ---- epilogue: combine partials, out = (O5 + Z^4 O1) / (S5 + Z^4 S1) ----
  float S1 = S1p[0] + S1p[1];
  S1 += __shfl_xor(S1, 32);
  float S5 = S5p[0] + S5p[1];
  S5 += __shfl_xor(S5, 32);
  const float z = S1, z2 = z * z, z4 = z2 * z2;
  const float inv = 1.0f / (S5 + z4 * S1);
#pragma unroll
  for (int dt = 0; dt < 2; ++dt)
#pragma unroll
    for (int i = 0; i < 4; ++i) {
      f4 o;
#pragma unroll
      for (int j = 0; j < 4; ++j)
        o[j] = (O5[dt][4 * i + j] + z4 * O1[dt][4 * i + j]) * inv;
      *(f4*)(O + base + (size_t)(q0 + lm) * 1024 + dt * 32 + 8 * i + 4 * hi) = o;
    }
}

extern "C" void kernel_launch(void* const* d_in, const int* in_sizes, int n_in,
                              void* d_out, int out_size, void* d_ws, size_t ws_size,
                              hipStream_t stream) {
  const float* q = (const float*)d_in[0];
  const float* k = (const float*)d_in[1];
  const float* v = (const float*)d_in[2];
  float* o = (float*)d_out;
  dsa_mfma<<<dim3(512), dim3(256), 0, stream>>>(q, k, v, o);
}

// Round 16
// 80.236 us; speedup vs baseline: 6.3017x; 1.0029x over previous
//
#include <hip/hip_runtime.h>
#include <math.h>

// DynamicSparseAttention via MFMA flash (f16 operands, fp32 accum):
// out = (O5 + Z^4 O1) / (S5 + Z^4 S1), e = 2^(s*log2e - m'), Z = S1.
// R16: exact revert to R14 (best proven-stable: 80.5us, no spill, replay-
//   deterministic). R15's staging-reg double-buffer failed post-timing
//   re-validation (nondeterministic divergence) and is abandoned.

typedef _Float16 h8 __attribute__((ext_vector_type(8)));
typedef _Float16 h2 __attribute__((ext_vector_type(2)));
typedef __fp16 g2 __attribute__((ext_vector_type(2)));
typedef float f4 __attribute__((ext_vector_type(4)));
typedef float f16v __attribute__((ext_vector_type(16)));
typedef unsigned int u4v __attribute__((ext_vector_type(4)));

constexpr int Sc = 2048, Hc = 16;
constexpr int KB = 64, NT = Sc / KB;
constexpr float LOG2E = 1.4426950408889634f;

__device__ __forceinline__ f16v mm32(h8 a, h8 b, f16v c) {
  return __builtin_amdgcn_mfma_f32_32x32x16_f16(a, b, c, 0, 0, 0);
}
__device__ __forceinline__ unsigned pku(float a, float b) {
  return __builtin_bit_cast(unsigned, __builtin_amdgcn_cvt_pkrtz(a, b));
}
__device__ __forceinline__ float fdot2(h2 a, float c) {  // a.x + a.y + c
  const g2 one2 = {(__fp16)1.0f, (__fp16)1.0f};
  return __builtin_amdgcn_fdot2(__builtin_bit_cast(g2, a), one2, c, false);
}

__global__ __launch_bounds__(256, 2) void dsa_mfma(
    const float* __restrict__ Q, const float* __restrict__ K,
    const float* __restrict__ V, float* __restrict__ O) {
  __shared__ __align__(16) _Float16 smem[4][2][64 * 64];  // [buf][K|V], 64 KB

  const int tid = threadIdx.x;
  const int w = tid >> 6, lane = tid & 63, lm = lane & 31, hi = lane >> 5;
  const int swz = (lm & 7) << 3;

  // XCD-bijective swizzle: 512 blocks = 8 XCD x 64; each XCD owns 4 heads.
  const int blk = blockIdx.x;
  const int ww = (blk & 7) * 64 + (blk >> 3);
  const int qtb = ww & 15, bh = ww >> 4;
  const int b = bh >> 4, h = bh & 15;

  const size_t base = ((size_t)b * Sc * Hc + h) * 64;  // row stride = 1024 floats
  const float* Qb = Q + base;
  const float* Kb = K + base;
  const float* Vb = V + base;
  const int q0 = qtb * 128 + w * 32;

  // ---- Q fragments (B-operand): lane holds Q[q0+lm][s*16 + hi*8 + j]*log2e ----
  h8 qf[4];
#pragma unroll
  for (int s = 0; s < 4; ++s) {
    const float* p = Qb + (size_t)(q0 + lm) * 1024 + s * 16 + hi * 8;
    f4 a = *(const f4*)p, c = *(const f4*)(p + 4);
#pragma unroll
    for (int i = 0; i < 4; ++i) {
      qf[s][i] = (_Float16)(a[i] * LOG2E);
      qf[s][4 + i] = (_Float16)(c[i] * LOG2E);
    }
  }

  f16v O1[2] = {}, O5[2] = {};                     // O^T[d][q], dtile 0/1
  float S1p[2] = {0.f, 0.f}, S5p[2] = {0.f, 0.f};  // fdot2 sum partials
  float mr = -INFINITY;

  // ---- staging: K row-owner (krow=tid&63, 16 floats), V column-gather ----
  f4 kf[4];
  float vreg[2][8];
  const int krow = tid & 63, kq = tid >> 6;       // K: row krow, float cols kq*16..+16
  const int vd = tid & 63, vo0 = (tid >> 6) * 2;  // V: d-col vd, k-octets vo0, vo0+1

  auto LOADK = [&](int k0) {
#pragma unroll
    for (int j = 0; j < 4; ++j)
      kf[j] = *(const f4*)(Kb + (size_t)(k0 + krow) * 1024 + kq * 16 + 4 * j);
  };
  auto LOADV = [&](int k0) {  // coalesced: 64 lanes read consecutive d
#pragma unroll
    for (int i = 0; i < 2; ++i) {
      const float* p = Vb + (size_t)(k0 + (vo0 + i) * 8) * 1024 + vd;
#pragma unroll
      for (int j = 0; j < 8; ++j) vreg[i][j] = p[(size_t)j * 1024];
    }
  };
  auto STORE = [&](int buf) {
    _Float16* Ks = &smem[buf][0][0];
    _Float16* Vts = &smem[buf][1][0];
#pragma unroll
    for (int i = 0; i < 2; ++i) {  // K: two b128 stores
      u4v wv = {pku(kf[2 * i][0], kf[2 * i][1]), pku(kf[2 * i][2], kf[2 * i][3]),
                pku(kf[2 * i + 1][0], kf[2 * i + 1][1]), pku(kf[2 * i + 1][2], kf[2 * i + 1][3])};
      int col = (kq * 16 + 8 * i) ^ ((krow & 7) << 3);
      *(h8*)&Ks[krow * 64 + col] = __builtin_bit_cast(h8, wv);
    }
#pragma unroll
    for (int i = 0; i < 2; ++i) {  // V^T: b128 stores
      u4v wv = {pku(vreg[i][0], vreg[i][1]), pku(vreg[i][2], vreg[i][3]),
                pku(vreg[i][4], vreg[i][5]), pku(vreg[i][6], vreg[i][7])};
      int col = ((vo0 + i) * 8) ^ ((vd & 7) << 3);
      *(h8*)&Vts[vd * 64 + col] = __builtin_bit_cast(h8, wv);
    }
  };

  auto QK = [&](int cur, f16v sc[2]) {
    const _Float16* Ks = &smem[cur][0][0];
    sc[0] = f16v{};
    sc[1] = f16v{};
    __builtin_amdgcn_s_setprio(1);
#pragma unroll
    for (int s = 0; s < 4; ++s) {
      h8 a0 = *(const h8*)&Ks[lm * 64 + ((s * 16 + hi * 8) ^ swz)];
      h8 a1 = *(const h8*)&Ks[(32 + lm) * 64 + ((s * 16 + hi * 8) ^ swz)];
      sc[0] = mm32(a0, qf[s], sc[0]);
      sc[1] = mm32(a1, qf[s], sc[1]);
    }
    __builtin_amdgcn_s_setprio(0);
  };

  auto PVX = [&](int cur, f16v sc[2], bool do5) {  // exp, in-reg P frags, PV + sums
    const _Float16* Vts = &smem[cur][1][0];
#pragma unroll
    for (int s = 0; s < 4; ++s) {
      const int kh = s >> 1, s8 = (s & 1) * 8, par = s & 1;
      float e[8];
#pragma unroll
      for (int j = 0; j < 8; ++j) e[j] = __builtin_amdgcn_exp2f(sc[kh][s8 + j] - mr);
      auto rA = __builtin_amdgcn_permlane32_swap(pku(e[0], e[1]), pku(e[4], e[5]), false, false);
      auto rB = __builtin_amdgcn_permlane32_swap(pku(e[2], e[3]), pku(e[6], e[7]), false, false);
      u4v bwE = {(unsigned)rA[0], (unsigned)rB[0], (unsigned)rA[1], (unsigned)rB[1]};
      h8 bE = __builtin_bit_cast(h8, bwE);
      h8 b2 = bE * bE, b4 = b2 * b2, b5 = b4 * bE;  // v_pk_mul_f16

      // S1 partial: every f16 in bE belongs to this lane's query (col = lm)
      float sp = fdot2(h2{bE[0], bE[1]}, 0.f);
      sp = fdot2(h2{bE[2], bE[3]}, sp);
      sp = fdot2(h2{bE[4], bE[5]}, sp);
      sp = fdot2(h2{bE[6], bE[7]}, sp);
      S1p[par] += sp;

      h8 v0 = *(const h8*)&Vts[lm * 64 + ((s * 16 + hi * 8) ^ swz)];
      h8 v1 = *(const h8*)&Vts[(32 + lm) * 64 + ((s * 16 + hi * 8) ^ swz)];
      __builtin_amdgcn_s_setprio(1);
      O1[0] = mm32(v0, bE, O1[0]);
      O1[1] = mm32(v1, bE, O1[1]);
      if (do5) {  // wave-uniform; skipped terms are exact +0
        float s5 = fdot2(h2{b5[0], b5[1]}, 0.f);
        s5 = fdot2(h2{b5[2], b5[3]}, s5);
        s5 = fdot2(h2{b5[4], b5[5]}, s5);
        s5 = fdot2(h2{b5[6], b5[7]}, s5);
        S5p[par] += s5;
        O5[0] = mm32(v0, b5, O5[0]);
        O5[1] = mm32(v1, b5, O5[1]);
      }
      __builtin_amdgcn_s_setprio(0);
    }
  };

  // ---- prologue: fill buffers 0,1; tile 2 in regs ----
  LOADK(0);
  LOADV(0);
  STORE(0);
  LOADK(KB);
  LOADV(KB);
  STORE(1);
  LOADK(2 * KB);
  LOADV(2 * KB);
  __syncthreads();

  // ---- main loop: 2 tiles per barrier; reads {t,t+1}&3, stores {t+2,t+3}&3 ----
#pragma unroll 1
  for (int t = 0; t < NT; t += 2) {
    if (t + 2 < NT) STORE((t + 2) & 3);
    if (t + 3 < NT) {
      LOADK((t + 3) * KB);
      LOADV((t + 3) * KB);
    }

    f16v s0[2], s1[2];
    QK(t & 3, s0);
    QK((t + 1) & 3, s1);

    // combined max over both tiles (128 k), single rescale check
    float m16[16];
#pragma unroll
    for (int r = 0; r < 16; ++r)
      m16[r] = fmaxf(fmaxf(s0[0][r], s0[1][r]), fmaxf(s1[0][r], s1[1][r]));
#pragma unroll
    for (int d = 8; d >= 1; d >>= 1)
#pragma unroll
      for (int r = 0; r < d; ++r) m16[r] = fmaxf(m16[r], m16[r + d]);
    float tm = fmaxf(m16[0], __shfl_xor(m16[0], 32));
    if (__any(tm > mr)) {
      float nm = fmaxf(mr, tm);
      float f = __builtin_amdgcn_exp2f(mr - nm);
      float f2 = f * f, f5 = f2 * f2 * f;
      mr = nm;
      S1p[0] *= f;
      S1p[1] *= f;
      S5p[0] *= f5;
      S5p[1] *= f5;
#pragma unroll
      for (int dt = 0; dt < 2; ++dt) {
        O1[dt] *= f;
        O5[dt] *= f5;
      }
    }
    // skip e5 accumulation iff 5*(tm-mr) <= -24.5: all f16 e^5 are exact +0
    const bool do5 = __any(tm > mr - 4.9f);

    PVX(t & 3, s0, do5);

    if (t + 3 < NT) STORE((t + 3) & 3);
    if (t + 4 < NT) {
      LOADK((t + 4) * KB);
      LOADV((t + 4) * KB);
    }

    PVX((t + 1) & 3, s1, do5);

    __syncthreads();
  }

  // ---- epilogue: combine partials, out = (O5 + Z^4 O1) / (S5 + Z^4 S1) ----
  float S1 = S1p[0] + S1p[1];
  S1 += __shfl_xor(S1, 32);
  float S5 = S5p[0] + S5p[1];
  S5 += __shfl_xor(S5, 32);
  const float z = S1, z2 = z * z, z4 = z2 * z2;
  const float inv = 1.0f / (S5 + z4 * S1);
#pragma unroll
  for (int dt = 0; dt < 2; ++dt)
#pragma unroll
    for (int i = 0; i < 4; ++i) {
      f4 o;
#pragma unroll
      for (int j = 0; j < 4; ++j)
        o[j] = (O5[dt][4 * i + j] + z4 * O1[dt][4 * i + j]) * inv;
      *(f4*)(O + base + (size_t)(q0 + lm) * 1024 + dt * 32 + 8 * i + 4 * hi) = o;
    }
}

extern "C" void kernel_launch(void* const* d_in, const int* in_sizes, int n_in,
                              void* d_out, int out_size, void* d_ws, size_t ws_size,
                              hipStream_t stream) {
  const float* q = (const float*)d_in[0];
  const float* k = (const float*)d_in[1];
  const float* v = (const float*)d_in[2];
  float* o = (float*)d_out;
  dsa_mfma<<<dim3(512), dim3(256), 0, stream>>>(q, k, v, o);
}